// Round 3
// baseline (50.512 us; speedup 1.0000x reference)
//
#include <hip/hip_runtime.h>

// MatryoshkaHarmonicMixing: out[b,s,d] = x[b,s,d]
//   + (d in [512,1024) && d%2==0) * s1 * x[b,s,d/2]
//   + (d in [512,2048) && d%4==0) * s2 * x[b,s,d/4]
//   + (d in [512,2048) && d%8==0) * s3 * x[b,s,d/8]
// where s_o = sigmoid(weights[o-1]).  D_MODEL=2048, MIN_CUTOFF=512.

#define D_MODEL 2048

typedef float v4f __attribute__((ext_vector_type(4)));  // clang-native: OK for nontemporal builtins

__device__ __forceinline__ v4f mhm_body(const float* __restrict__ x,
                                        long long i,
                                        float s1, float s2, float s3)
{
    const long long e0 = i << 2;                 // first element of this float4
    const int d0 = (int)(e0 & (D_MODEL - 1));    // position within the row
    const long long row = e0 - d0;               // row start (flat)

    v4f v = reinterpret_cast<const v4f*>(x)[i];

    if (d0 >= 512) {
        if (d0 < 1024) {                         // octave 1 (stride 2)
            v.x += s1 * x[row + (d0 >> 1)];
            v.z += s1 * x[row + (d0 >> 1) + 1];
        }
        v.x += s2 * x[row + (d0 >> 2)];          // octave 2 (stride 4)
        if ((d0 & 7) == 0) {                     // octave 3 (stride 8)
            v.x += s3 * x[row + (d0 >> 3)];
        }
    }
    return v;
}

__global__ __launch_bounds__(256) void mhm_kernel(
    const float* __restrict__ x,
    const float* __restrict__ w,
    float* __restrict__ out,
    long long n4)
{
    const float s1 = 1.0f / (1.0f + expf(-w[0]));
    const float s2 = 1.0f / (1.0f + expf(-w[1]));
    const float s3 = 1.0f / (1.0f + expf(-w[2]));

    const long long stride = (long long)gridDim.x * blockDim.x;
    long long i = (long long)blockIdx.x * blockDim.x + threadIdx.x;

    // 2x unrolled grid-stride: two independent load/compute/store chains
    // in flight per iteration.
    for (; i + stride < n4; i += 2 * stride) {
        const long long j = i + stride;
        v4f va = mhm_body(x, i, s1, s2, s3);
        v4f vb = mhm_body(x, j, s1, s2, s3);
        __builtin_nontemporal_store(va, reinterpret_cast<v4f*>(out) + i);
        __builtin_nontemporal_store(vb, reinterpret_cast<v4f*>(out) + j);
    }
    if (i < n4) {
        v4f va = mhm_body(x, i, s1, s2, s3);
        __builtin_nontemporal_store(va, reinterpret_cast<v4f*>(out) + i);
    }
}

extern "C" void kernel_launch(void* const* d_in, const int* in_sizes, int n_in,
                              void* d_out, int out_size, void* d_ws, size_t ws_size,
                              hipStream_t stream) {
    const float* x = (const float*)d_in[0];     // (4, 4096, 2048) f32
    const float* w = (const float*)d_in[1];     // (3,) f32
    float* out = (float*)d_out;

    const long long n = (long long)out_size;    // 4*4096*2048
    const long long n4 = n >> 2;                // float4 count

    const int threads = 256;
    int blocks = 2048;                          // 8 blocks/CU, grid-stride
    long long needed = (n4 + threads - 1) / threads;
    if (needed < blocks) blocks = (int)needed;

    mhm_kernel<<<blocks, threads, 0, stream>>>(x, w, out, n4);
}

// Round 4
// 48.069 us; speedup vs baseline: 1.0508x; 1.0508x over previous
//
#include <hip/hip_runtime.h>

// MatryoshkaHarmonicMixing: out[b,s,d] = x[b,s,d]
//   + (d in [512,1024) && d%2==0) * s1 * x[b,s,d/2]
//   + (d in [512,2048) && d%4==0) * s2 * x[b,s,d/4]
//   + (d in [512,2048) && d%8==0) * s3 * x[b,s,d/8]
// where s_o = sigmoid(weights[o-1]).  D_MODEL=2048, MIN_CUTOFF=512.
//
// One float4 per thread, exact grid (no grid-stride loop): pure streaming.

#define D_MODEL 2048

typedef float v4f __attribute__((ext_vector_type(4)));

__global__ __launch_bounds__(256) void mhm_kernel(
    const float* __restrict__ x,
    const float* __restrict__ w,
    float* __restrict__ out)
{
    const float s1 = 1.0f / (1.0f + expf(-w[0]));
    const float s2 = 1.0f / (1.0f + expf(-w[1]));
    const float s3 = 1.0f / (1.0f + expf(-w[2]));

    const long long i = (long long)blockIdx.x * blockDim.x + threadIdx.x;
    const long long e0 = i << 2;                  // first element of this float4
    const int d0 = (int)(e0 & (D_MODEL - 1));     // position within the row
    const long long row = e0 - d0;                // row start (flat)

    v4f v = reinterpret_cast<const v4f*>(x)[i];

    if (d0 >= 512) {
        if (d0 < 1024) {                          // octave 1 (stride 2): pair load
            const float2 p = *reinterpret_cast<const float2*>(&x[row + (d0 >> 1)]);
            v.x += s1 * p.x;
            v.z += s1 * p.y;
        }
        v.x += s2 * x[row + (d0 >> 2)];           // octave 2 (stride 4)
        if ((d0 & 7) == 0) {                      // octave 3 (stride 8)
            v.x += s3 * x[row + (d0 >> 3)];
        }
    }

    __builtin_nontemporal_store(v, reinterpret_cast<v4f*>(out) + i);
}

extern "C" void kernel_launch(void* const* d_in, const int* in_sizes, int n_in,
                              void* d_out, int out_size, void* d_ws, size_t ws_size,
                              hipStream_t stream) {
    const float* x = (const float*)d_in[0];     // (4, 4096, 2048) f32
    const float* w = (const float*)d_in[1];     // (3,) f32
    float* out = (float*)d_out;

    const long long n = (long long)out_size;    // 4*4096*2048 = 33554432
    const long long n4 = n >> 2;                // 8388608 float4s
    const int threads = 256;
    const int blocks = (int)((n4 + threads - 1) / threads);  // 32768, exact

    mhm_kernel<<<blocks, threads, 0, stream>>>(x, w, out);
}

// Round 5
// 42.358 us; speedup vs baseline: 1.1925x; 1.1348x over previous
//
#include <hip/hip_runtime.h>

// MatryoshkaHarmonicMixing: out[b,s,d] = x[b,s,d]
//   + (d in [512,1024) && d%2==0) * s1 * x[b,s,d/2]
//   + (d in [512,2048) && d%4==0) * s2 * x[b,s,d/4]
//   + (d in [512,2048) && d%8==0) * s3 * x[b,s,d/8]
// with s_o = sigmoid(weights[o-1]).  D_MODEL=2048, MIN_CUTOFF=512.
//
// Key fact: every gather SOURCE index lies in [64, 512) of the same row.
// One block per row: stage x[row, 64:512) in LDS (1.75 KB), gathers become
// LDS reads; all global traffic is perfectly-coalesced 16 B/lane streams.

#define D_MODEL 2048

typedef float v4f __attribute__((ext_vector_type(4)));

__global__ __launch_bounds__(256) void mhm_kernel(
    const float* __restrict__ x,
    const float* __restrict__ w,
    float* __restrict__ out)
{
    __shared__ float lds[512];   // holds x[row, 0:512) (only [64,512) written)

    const float s1 = 1.0f / (1.0f + expf(-w[0]));
    const float s2 = 1.0f / (1.0f + expf(-w[1]));
    const float s3 = 1.0f / (1.0f + expf(-w[2]));

    const int t = threadIdx.x;
    const long long row4 = (long long)blockIdx.x * (D_MODEL / 4); // float4 idx of row start
    const v4f* __restrict__ x4 = reinterpret_cast<const v4f*>(x);
    v4f* __restrict__ o4 = reinterpret_cast<v4f*>(out);

    v4f a = x4[row4 + t];         // d = 4t       in [0,1024)
    v4f b = x4[row4 + 256 + t];   // d = 1024+4t  in [1024,2048)

    // Threads t in [16,128) own floats [64,512) — the full gather-source window.
    if (t >= 16 && t < 128) {
        reinterpret_cast<v4f*>(lds)[t] = a;
    }
    __syncthreads();

    // ---- A half: d = 4t ----
    if (t >= 128) {               // d in [512,1024): oct1 + oct2 + oct3
        // octave 1 (stride 2): src pair at d/2, d/2+1  (dword idx 2t, 2t+1)
        const float2 p = *reinterpret_cast<const float2*>(&lds[t << 1]);
        a.x += s1 * p.x;
        a.z += s1 * p.y;
        // octave 2 (stride 4): src = d/4 = t
        a.x += s2 * lds[t];
        // octave 3 (stride 8): d%8==0 <=> t even; src = d/8 = t/2
        if ((t & 1) == 0) a.x += s3 * lds[t >> 1];
    }
    __builtin_nontemporal_store(a, &o4[row4 + t]);

    // ---- B half: d = 1024 + 4t, all in [1024,2048): oct2 + oct3 ----
    b.x += s2 * lds[256 + t];                       // src = d/4 = 256 + t
    if ((t & 1) == 0) b.x += s3 * lds[128 + (t >> 1)]; // src = d/8
    __builtin_nontemporal_store(b, &o4[row4 + 256 + t]);
}

extern "C" void kernel_launch(void* const* d_in, const int* in_sizes, int n_in,
                              void* d_out, int out_size, void* d_ws, size_t ws_size,
                              hipStream_t stream) {
    const float* x = (const float*)d_in[0];     // (4, 4096, 2048) f32
    const float* w = (const float*)d_in[1];     // (3,) f32
    float* out = (float*)d_out;

    const int rows = out_size / D_MODEL;        // 4*4096 = 16384
    mhm_kernel<<<rows, 256, 0, stream>>>(x, w, out);
}